// Round 5
// baseline (2969.078 us; speedup 1.0000x reference)
//
#include <hip/hip_runtime.h>
#include <cstdint>
#include <cstddef>

#define IMPOSSIBLE -10000.0f
#define INV_LN2 1.44269504088896340736f
#define LN2 0.69314718055994530942f

constexpr int B = 64;
constexpr int T = 2048;
constexpr int N = 128;

// One WAVE (64 threads) per chain. Lane l owns states 2l, 2l+1.
// Exp-domain recurrence: aexp'_j = (sum_i aexp_i * E_ij) * emexp_j, with
// E = exp(trans) (0 where forbidden), emexp = exp(em) (0 where sup-clamped).
// True alpha = aexp * 2^Mtot. Rescale by exact pow2 every 8 steps (anchor =
// readfirstlane of state0's pre-emission sum). No barriers: same-wave DS ops
// are in-order; p exchange = ds_write_b64 + broadcast ds_read_b128.
// E columns (256 f32) live in VGPRs. emexp computed at prefetch (depth 3),
// off the dependent chain. Bool inputs are int32. Output via z_ws (pure).
__global__ __launch_bounds__(64, 1) void crf_chain_kernel(
    const float* __restrict__ emissions,    // [B,T,N]
    const int* __restrict__ mask,           // [B,T]
    const int* __restrict__ target,         // [B,T,N]
    const float* __restrict__ transitions,  // [N,N]
    const float* __restrict__ start_tr,     // [N]
    const float* __restrict__ end_tr,       // [N]
    const int* __restrict__ forb,           // [N,N]
    const int* __restrict__ start_forb,     // [N]
    const int* __restrict__ end_forb,       // [N]
    float* __restrict__ z_ws)               // [128]
{
    const int chain = blockIdx.x;  // 0..127
    const int c = chain >> 6;      // 0 = supervised, 1 = full
    const int b = chain & 63;
    const int lane = (int)threadIdx.x;  // 0..63
    const int s0 = lane << 1, s1 = s0 + 1;
    const bool sup = (c == 0);

    __shared__ __align__(16) float p_lds[128];

    // ---- sequence length ----
    int lsum = 0;
    for (int k = lane; k < T; k += 64) lsum += (mask[b * T + k] != 0);
    #pragma unroll
    for (int d = 1; d < 64; d <<= 1) lsum += __shfl_xor(lsum, d);
    const int tlast = lsum - 1;

    // ---- E columns for states s0, s1 -> VGPRs ----
    float eA[128], eB[128];
    #pragma unroll
    for (int i = 0; i < 128; ++i) {
        const float2 tv = *reinterpret_cast<const float2*>(&transitions[i * N + s0]);
        const int2 fb = *reinterpret_cast<const int2*>(&forb[i * N + s0]);
        eA[i] = fb.x ? 0.0f : __expf(tv.x);
        eB[i] = fb.y ? 0.0f : __expf(tv.y);
    }

    const float* embase = emissions + (size_t)b * T * N;
    const int* tgbase = target + (size_t)b * T * N;

    // ---- t = 0 init (log2 domain once, then exp domain forever) ----
    const float stA = start_forb[s0] ? IMPOSSIBLE : start_tr[s0];
    const float stB = start_forb[s1] ? IMPOSSIBLE : start_tr[s1];
    const float2 em0 = *reinterpret_cast<const float2*>(&embase[s0]);
    int2 tg0 = make_int2(1, 1);
    if (sup) tg0 = *reinterpret_cast<const int2*>(&tgbase[s0]);
    const float v0 = ((tg0.x ? em0.x : IMPOSSIBLE) + stA) * INV_LN2;
    const float v1 = ((tg0.y ? em0.y : IMPOSSIBLE) + stB) * INV_LN2;

    float mx = fmaxf(v0, v1);
    #pragma unroll
    for (int d = 1; d < 64; d <<= 1) mx = fmaxf(mx, __shfl_xor(mx, d));
    float Mtot = rintf(mx);
    float a0 = exp2f(v0 - Mtot);
    float a1 = exp2f(v1 - Mtot);
    float sv0 = a0, sv1 = a1, svM = Mtot;  // covers tlast == 0
    *reinterpret_cast<float2*>(&p_lds[s0]) = make_float2(a0, a1);

    // ---- emission prefetch pipeline, depth 3, exp computed off-path ----
    // invariant at top of iter t: fx = emexp(t); rB/gB raw(t+1); rC/gC raw(t+2)
    float2 r1 = *reinterpret_cast<const float2*>(&embase[(size_t)1 * N + s0]);
    int2 g1 = make_int2(1, 1);
    float2 rB = *reinterpret_cast<const float2*>(&embase[(size_t)2 * N + s0]);
    int2 gB = make_int2(1, 1);
    float2 rC = *reinterpret_cast<const float2*>(&embase[(size_t)3 * N + s0]);
    int2 gC = make_int2(1, 1);
    if (sup) {
        g1 = *reinterpret_cast<const int2*>(&tgbase[(size_t)1 * N + s0]);
        gB = *reinterpret_cast<const int2*>(&tgbase[(size_t)2 * N + s0]);
        gC = *reinterpret_cast<const int2*>(&tgbase[(size_t)3 * N + s0]);
    }
    float fxA = g1.x ? __expf(r1.x) : 0.0f;
    float fxB = g1.y ? __expf(r1.y) : 0.0f;

    #pragma unroll 1
    for (int t = 1; t < T; ++t) {
        // matvec: s_j = sum_i p[i] * E[i][j], broadcast LDS reads
        const float4* pp = reinterpret_cast<const float4*>(p_lds);
        float s0a = 0.f, s0b = 0.f, s0c = 0.f, s0d = 0.f;
        float s1a = 0.f, s1b = 0.f, s1c = 0.f, s1d = 0.f;
        #pragma unroll
        for (int kk = 0; kk < 8; ++kk) {
            const float4 q0 = pp[4 * kk + 0];
            const float4 q1 = pp[4 * kk + 1];
            const float4 q2 = pp[4 * kk + 2];
            const float4 q3 = pp[4 * kk + 3];
            const int i0 = 16 * kk;
            s0a = fmaf(q0.x, eA[i0 + 0], s0a);  s0a = fmaf(q0.y, eA[i0 + 1], s0a);
            s0a = fmaf(q0.z, eA[i0 + 2], s0a);  s0a = fmaf(q0.w, eA[i0 + 3], s0a);
            s0b = fmaf(q1.x, eA[i0 + 4], s0b);  s0b = fmaf(q1.y, eA[i0 + 5], s0b);
            s0b = fmaf(q1.z, eA[i0 + 6], s0b);  s0b = fmaf(q1.w, eA[i0 + 7], s0b);
            s0c = fmaf(q2.x, eA[i0 + 8], s0c);  s0c = fmaf(q2.y, eA[i0 + 9], s0c);
            s0c = fmaf(q2.z, eA[i0 + 10], s0c); s0c = fmaf(q2.w, eA[i0 + 11], s0c);
            s0d = fmaf(q3.x, eA[i0 + 12], s0d); s0d = fmaf(q3.y, eA[i0 + 13], s0d);
            s0d = fmaf(q3.z, eA[i0 + 14], s0d); s0d = fmaf(q3.w, eA[i0 + 15], s0d);
            s1a = fmaf(q0.x, eB[i0 + 0], s1a);  s1a = fmaf(q0.y, eB[i0 + 1], s1a);
            s1a = fmaf(q0.z, eB[i0 + 2], s1a);  s1a = fmaf(q0.w, eB[i0 + 3], s1a);
            s1b = fmaf(q1.x, eB[i0 + 4], s1b);  s1b = fmaf(q1.y, eB[i0 + 5], s1b);
            s1b = fmaf(q1.z, eB[i0 + 6], s1b);  s1b = fmaf(q1.w, eB[i0 + 7], s1b);
            s1c = fmaf(q2.x, eB[i0 + 8], s1c);  s1c = fmaf(q2.y, eB[i0 + 9], s1c);
            s1c = fmaf(q2.z, eB[i0 + 10], s1c); s1c = fmaf(q2.w, eB[i0 + 11], s1c);
            s1d = fmaf(q3.x, eB[i0 + 12], s1d); s1d = fmaf(q3.y, eB[i0 + 13], s1d);
            s1d = fmaf(q3.z, eB[i0 + 14], s1d); s1d = fmaf(q3.w, eB[i0 + 15], s1d);
        }
        const float ss0 = (s0a + s0b) + (s0c + s0d);
        const float ss1 = (s1a + s1b) + (s1c + s1d);

        // exact-pow2 rescale every 8 steps; anchor = state0's pre-em sum
        float sc = 1.0f;
        if ((t & 7) == 0) {
            const float anchor = __int_as_float(
                __builtin_amdgcn_readfirstlane(__float_as_int(ss0)));
            const float kf = rintf(__log2f(fmaxf(anchor, 1e-35f)));
            sc = exp2f(-kf);
            Mtot += kf;
        }

        const float na = ss0 * fxA * sc;
        const float nb = ss1 * fxB * sc;

        if (t == tlast) { sv0 = na; sv1 = nb; svM = Mtot; }

        *reinterpret_cast<float2*>(&p_lds[s0]) = make_float2(na, nb);

        // prefetch raw t+3; convert raw t+1 -> emexp (off dependent chain)
        float2 rN = make_float2(0.0f, 0.0f);
        int2 gN = make_int2(1, 1);
        if (t + 3 < T) {
            rN = *reinterpret_cast<const float2*>(&embase[(size_t)(t + 3) * N + s0]);
            if (sup) gN = *reinterpret_cast<const int2*>(&tgbase[(size_t)(t + 3) * N + s0]);
        }
        fxA = gB.x ? __expf(rB.x) : 0.0f;
        fxB = gB.y ? __expf(rB.y) : 0.0f;
        rB = rC; gB = gC;
        rC = rN; gC = gN;
    }

    // ---- z = log( sum_j sv_j * exp(en_j) ) + LN2*svM ----
    const float2 en2 = *reinterpret_cast<const float2*>(&end_tr[s0]);
    const int2 ef2 = *reinterpret_cast<const int2*>(&end_forb[s0]);
    float term = sv0 * (ef2.x ? 0.0f : __expf(en2.x))
               + sv1 * (ef2.y ? 0.0f : __expf(en2.y));
    #pragma unroll
    for (int d = 1; d < 64; d <<= 1) term += __shfl_xor(term, d);
    const float z = LN2 * svM + __logf(term);

    if (lane == 0) z_ws[chain] = z;
}

__global__ void crf_combine_kernel(const float* __restrict__ z_ws,
                                   float* __restrict__ out) {
    const int b = (int)threadIdx.x;
    if (b < B) out[b] = z_ws[B + b] - z_ws[b];
}

extern "C" void kernel_launch(void* const* d_in, const int* in_sizes, int n_in,
                              void* d_out, int out_size, void* d_ws, size_t ws_size,
                              hipStream_t stream) {
    const float* emissions = (const float*)d_in[0];
    const int* mask = (const int*)d_in[1];
    const int* target = (const int*)d_in[2];
    const float* transitions = (const float*)d_in[3];
    const float* start_tr = (const float*)d_in[4];
    const float* end_tr = (const float*)d_in[5];
    const int* forb = (const int*)d_in[6];
    const int* start_forb = (const int*)d_in[7];
    const int* end_forb = (const int*)d_in[8];
    float* out = (float*)d_out;
    float* z_ws = (float*)d_ws;

    crf_chain_kernel<<<dim3(2 * B), dim3(64), 0, stream>>>(
        emissions, mask, target, transitions, start_tr, end_tr,
        forb, start_forb, end_forb, z_ws);
    crf_combine_kernel<<<dim3(1), dim3(64), 0, stream>>>(z_ws, out);
}

// Round 6
// 1384.437 us; speedup vs baseline: 2.1446x; 2.1446x over previous
//
#include <hip/hip_runtime.h>
#include <cstdint>
#include <cstddef>

#define IMPOSSIBLE -10000.0f
#define INV_LN2 1.44269504088896340736f
#define LN2 0.69314718055994530942f

constexpr int B = 64;
constexpr int T = 2048;
constexpr int N = 128;

// One block per chain (c,b), 4 waves / 256 threads.
// j = (wave<<5)|(lane&31); h = lane>>5 selects i-half [64h, 64h+64).
// Exp-domain: p'_j = (sum_i p_i * E_ij) * exp(em_j); true alpha = log(p) + LN2*Mtot.
// E = exp(trans) (0 if forbidden) in VGPRs (64/lane). One raw barrier/step.
// Cross-half combine via v_permlane32_swap_b32 (VALU, not ds_bpermute).
// Rescale by exact pow2 every 8 steps; anchor = prev step's state-0 pre-em sum
// (double-buffered LDS slot, read off-path). Bool inputs are int32 per ABI.
// Pure function of d_in: plain stores to z_ws, no atomics, no memset.
__global__ __launch_bounds__(256, 1) void crf_chain_kernel(
    const float* __restrict__ emissions,    // [B,T,N]
    const int* __restrict__ mask,           // [B,T]
    const int* __restrict__ target,         // [B,T,N]
    const float* __restrict__ transitions,  // [N,N]
    const float* __restrict__ start_tr,     // [N]
    const float* __restrict__ end_tr,       // [N]
    const int* __restrict__ forb,           // [N,N]
    const int* __restrict__ start_forb,     // [N]
    const int* __restrict__ end_forb,       // [N]
    float* __restrict__ z_ws)               // [128]
{
    const int chain = blockIdx.x;  // 0..127
    const int c = chain >> 6;      // 0 = supervised, 1 = full
    const int b = chain & 63;
    const int tid = (int)threadIdx.x;
    const int wave = tid >> 6;
    const int lane = tid & 63;
    const int h = lane >> 5;
    const int j = (wave << 5) | (lane & 31);
    const bool sup = (c == 0);

    __shared__ __align__(16) float p_buf[2][128];
    __shared__ float slotS[2];
    __shared__ float wred[4];
    __shared__ int lred[4];

    // ---- sequence length ----
    int lsum = 0;
    for (int k = tid; k < T; k += 256) lsum += (mask[b * T + k] != 0);
    #pragma unroll
    for (int d = 1; d < 64; d <<= 1) lsum += __shfl_xor(lsum, d);
    if (lane == 0) lred[wave] = lsum;
    __syncthreads();
    const int tlast = (lred[0] + lred[1] + lred[2] + lred[3]) - 1;

    // ---- E column slice: e[k] = exp(trans[64h+k][j]) or 0 ----
    float e[64];
    #pragma unroll
    for (int k = 0; k < 64; ++k) {
        const int i = (h << 6) + k;
        const float tv = transitions[i * N + j];
        e[k] = forb[i * N + j] ? 0.0f : __expf(tv);
    }

    const float* embase = emissions + (size_t)b * T * N;
    const int* tgbase = target + (size_t)b * T * N;

    // ---- t = 0 (log2 domain once) ----
    const float st = start_forb[j] ? IMPOSSIBLE : start_tr[j];
    float em0 = embase[j];
    if (sup && !tgbase[j]) em0 = IMPOSSIBLE;
    const float a0l = (em0 + st) * INV_LN2;

    float mx = a0l;
    #pragma unroll
    for (int d = 1; d < 64; d <<= 1) mx = fmaxf(mx, __shfl_xor(mx, d));
    if (lane == 0) wred[wave] = mx;
    __syncthreads();
    mx = fmaxf(fmaxf(wred[0], wred[1]), fmaxf(wred[2], wred[3]));

    float Mtot = rintf(mx);
    const float p0 = exp2f(a0l - Mtot);
    float svE = p0, svM = Mtot;  // covers tlast == 0
    if (h == 0) p_buf[0][j] = p0;
    if (tid == 0) { slotS[0] = 1.0f; slotS[1] = 1.0f; }

    // ---- emission prefetch depth 3; fx = exp(em(t)) computed off-path ----
    // invariant at top of iter t: fx = emexp(t); (rB,gB)=raw(t+1); (rC,gC)=raw(t+2)
    const float* emP = embase + j;
    const int* tgP = tgbase + j;
    float r1 = emP[(size_t)1 * N];
    int g1 = sup ? tgP[(size_t)1 * N] : 1;
    float rB = emP[(size_t)2 * N];
    int gB = sup ? tgP[(size_t)2 * N] : 1;
    float rC = emP[(size_t)3 * N];
    int gC = sup ? tgP[(size_t)3 * N] : 1;
    float fx = g1 ? __expf(r1) : 0.0f;

    #pragma unroll 2
    for (int t = 1; t < T; ++t) {
        // raw barrier: drain LDS only; global loads stay in flight
        asm volatile("s_waitcnt lgkmcnt(0)\n\ts_barrier" ::: "memory");

        const int cur = t & 1, prv = cur ^ 1;
        const float slotv = slotS[prv];  // read every step; latency hides under matvec

        // matvec: s_j(half h) = sum_k p[64h+k] * e[k]
        const float4* p4 = reinterpret_cast<const float4*>(&p_buf[prv][h << 6]);
        float a0 = 0.f, a1 = 0.f, a2 = 0.f, a3 = 0.f;
        #pragma unroll
        for (int k = 0; k < 16; k += 4) {
            const float4 v0 = p4[k], v1 = p4[k + 1], v2 = p4[k + 2], v3 = p4[k + 3];
            a0 = fmaf(v0.x, e[4*k+0], a0);  a0 = fmaf(v0.y, e[4*k+1], a0);
            a0 = fmaf(v0.z, e[4*k+2], a0);  a0 = fmaf(v0.w, e[4*k+3], a0);
            a1 = fmaf(v1.x, e[4*k+4], a1);  a1 = fmaf(v1.y, e[4*k+5], a1);
            a1 = fmaf(v1.z, e[4*k+6], a1);  a1 = fmaf(v1.w, e[4*k+7], a1);
            a2 = fmaf(v2.x, e[4*k+8], a2);  a2 = fmaf(v2.y, e[4*k+9], a2);
            a2 = fmaf(v2.z, e[4*k+10], a2); a2 = fmaf(v2.w, e[4*k+11], a2);
            a3 = fmaf(v3.x, e[4*k+12], a3); a3 = fmaf(v3.y, e[4*k+13], a3);
            a3 = fmaf(v3.z, e[4*k+14], a3); a3 = fmaf(v3.w, e[4*k+15], a3);
        }
        const float s = (a0 + a1) + (a2 + a3);

        // cross-half sum via permlane32_swap: x=(s_lo,s_lo), y=(s_hi,s_hi)
        float x = s, y = s;
        asm volatile("v_permlane32_swap_b32 %0, %1" : "+v"(x), "+v"(y));
        const float stot = x + y;

        // pow2 rescale every 8 steps (uniform: slotv identical in all threads)
        float sc = 1.0f;
        if ((t & 7) == 0) {
            const float kf = rintf(__log2f(fmaxf(slotv, 1e-35f)));
            sc = exp2f(-kf);
            Mtot += kf;
        }

        const float na = stot * fx * sc;
        if (t == tlast) { svE = na; svM = Mtot; }

        if (h == 0) p_buf[cur][j] = na;
        if (tid == 0) slotS[cur] = stot;  // pre-emission sum of state 0

        // prefetch raw(t+3); produce fx for t+1 from (rB,gB)
        float rN = 0.0f; int gN = 1;
        if (t + 3 < T) {
            rN = emP[(size_t)(t + 3) * N];
            if (sup) gN = tgP[(size_t)(t + 3) * N];
        }
        fx = gB ? __expf(rB) : 0.0f;
        rB = rC; gB = gC;
        rC = rN; gC = gN;
    }

    // ---- z = LN2*svM + log( sum_j svE_j * exp(en_j) ) ; j duplicated x2 ----
    const float en = end_forb[j] ? IMPOSSIBLE : end_tr[j];
    float term = svE * __expf(en);

    #pragma unroll
    for (int d = 1; d < 64; d <<= 1) term += __shfl_xor(term, d);
    __syncthreads();
    if (lane == 0) wred[wave] = term;
    __syncthreads();
    const float tot = (wred[0] + wred[1]) + (wred[2] + wred[3]);  // = 2 * sum
    const float z = LN2 * svM + __logf(tot * 0.5f);

    if (tid == 0) z_ws[chain] = z;
}

__global__ void crf_combine_kernel(const float* __restrict__ z_ws,
                                   float* __restrict__ out) {
    const int b = (int)threadIdx.x;
    if (b < B) out[b] = z_ws[B + b] - z_ws[b];
}

extern "C" void kernel_launch(void* const* d_in, const int* in_sizes, int n_in,
                              void* d_out, int out_size, void* d_ws, size_t ws_size,
                              hipStream_t stream) {
    const float* emissions = (const float*)d_in[0];
    const int* mask = (const int*)d_in[1];
    const int* target = (const int*)d_in[2];
    const float* transitions = (const float*)d_in[3];
    const float* start_tr = (const float*)d_in[4];
    const float* end_tr = (const float*)d_in[5];
    const int* forb = (const int*)d_in[6];
    const int* start_forb = (const int*)d_in[7];
    const int* end_forb = (const int*)d_in[8];
    float* out = (float*)d_out;
    float* z_ws = (float*)d_ws;

    crf_chain_kernel<<<dim3(2 * B), dim3(256), 0, stream>>>(
        emissions, mask, target, transitions, start_tr, end_tr,
        forb, start_forb, end_forb, z_ws);
    crf_combine_kernel<<<dim3(1), dim3(64), 0, stream>>>(z_ws, out);
}

// Round 8
// 1263.640 us; speedup vs baseline: 2.3496x; 1.0956x over previous
//
#include <hip/hip_runtime.h>
#include <cstdint>
#include <cstddef>

#define IMPOSSIBLE -10000.0f
#define INV_LN2 1.44269504088896340736f
#define LN2 0.69314718055994530942f

constexpr int B = 64;
constexpr int T = 2048;
constexpr int N = 128;

typedef _Float16 h2 __attribute__((ext_vector_type(2)));
typedef _Float16 h8 __attribute__((ext_vector_type(8)));

// One block per chain (c,b), 4 waves / 256 threads.
// j = (wave<<5)|(lane&31); h = lane>>5 selects i-half [64h, 64h+64).
// Exp-domain: p'_j = (sum_i p_i E_ij) * exp(em_j) / psum, p stored f16, where
// psum = sum_j p_j of the CURRENT stored array (self-referential normalizer:
// p' <= max(E)*exp(em) ~ 222 unconditionally -- no scale oscillator, f16-safe;
// the r7 stale-anchor scheme was an undamped oscillator and NaN'd).
// psum accumulated during the matvec (dot2 vs {1,1}), merged via permlane.
// Matvec: 8 rotated ds_read_b128 (lane starts at chunk lane&7: 8 distinct
// chunks/instr, 2-way inter-half conflict = free) + 32 v_dot2_f32_f16.
// Mtot accumulates log2(psum). One raw barrier/step (lgkmcnt only).
// Bool inputs are int32 per ABI. Pure function of d_in (no atomics/memset).
__global__ __launch_bounds__(256, 1) void crf_chain_kernel(
    const float* __restrict__ emissions,    // [B,T,N]
    const int* __restrict__ mask,           // [B,T]
    const int* __restrict__ target,         // [B,T,N]
    const float* __restrict__ transitions,  // [N,N]
    const float* __restrict__ start_tr,     // [N]
    const float* __restrict__ end_tr,       // [N]
    const int* __restrict__ forb,           // [N,N]
    const int* __restrict__ start_forb,     // [N]
    const int* __restrict__ end_forb,       // [N]
    float* __restrict__ z_ws)               // [128]
{
    const int chain = blockIdx.x;  // 0..127
    const int c = chain >> 6;      // 0 = supervised, 1 = full
    const int b = chain & 63;
    const int tid = (int)threadIdx.x;
    const int wave = tid >> 6;
    const int lane = tid & 63;
    const int h = lane >> 5;
    const int j = (wave << 5) | (lane & 31);
    const bool sup = (c == 0);

    __shared__ __align__(16) _Float16 p_buf[2][128];
    __shared__ float wred[4];
    __shared__ int lred[4];

    // ---- sequence length ----
    int lsum = 0;
    for (int k = tid; k < T; k += 256) lsum += (mask[b * T + k] != 0);
    #pragma unroll
    for (int d = 1; d < 64; d <<= 1) lsum += __shfl_xor(lsum, d);
    if (lane == 0) lred[wave] = lsum;
    __syncthreads();
    const int tlast = (lred[0] + lred[1] + lred[2] + lred[3]) - 1;

    // ---- E column slice in f16 pairs, pre-rotated by lane&7 ----
    // e2[4k+m] pairs with p chunk cch=((lane&7)+k)&7, elements i=64h+8cch+2m..+1
    h2 e2[32];
    #pragma unroll
    for (int k = 0; k < 8; ++k) {
        const int cch = ((lane & 7) + k) & 7;
        const int ib = (h << 6) + (cch << 3);
        #pragma unroll
        for (int m = 0; m < 4; ++m) {
            const int i0 = ib + (m << 1);
            const float f0 = forb[i0 * N + j] ? 0.0f : __expf(transitions[i0 * N + j]);
            const float f1 = forb[(i0 + 1) * N + j] ? 0.0f : __expf(transitions[(i0 + 1) * N + j]);
            e2[(k << 2) + m] = h2{(_Float16)f0, (_Float16)f1};
        }
    }

    const float* embase = emissions + (size_t)b * T * N;
    const int* tgbase = target + (size_t)b * T * N;

    // ---- t = 0 (log2 domain once; p normalized so max = 1) ----
    const float st = start_forb[j] ? IMPOSSIBLE : start_tr[j];
    float em0 = embase[j];
    if (sup && !tgbase[j]) em0 = IMPOSSIBLE;
    const float a0l = (em0 + st) * INV_LN2;

    float mx = a0l;
    #pragma unroll
    for (int d = 1; d < 64; d <<= 1) mx = fmaxf(mx, __shfl_xor(mx, d));
    if (lane == 0) wred[wave] = mx;
    __syncthreads();
    mx = fmaxf(fmaxf(wred[0], wred[1]), fmaxf(wred[2], wred[3]));

    float Mtot = rintf(mx);
    const float p0 = exp2f(a0l - Mtot);
    float svE = p0, svM = Mtot;  // covers tlast == 0
    if (h == 0) p_buf[0][j] = (_Float16)p0;

    // ---- emission prefetch depth 3; fx = exp(em(t)) computed off-path ----
    const float* emP = embase + j;
    const int* tgP = tgbase + j;
    float r1 = emP[(size_t)1 * N];
    int g1 = sup ? tgP[(size_t)1 * N] : 1;
    float rB = emP[(size_t)2 * N];
    int gB = sup ? tgP[(size_t)2 * N] : 1;
    float rC = emP[(size_t)3 * N];
    int gC = sup ? tgP[(size_t)3 * N] : 1;
    float fx = g1 ? __expf(r1) : 0.0f;

    const _Float16* pb0 = &p_buf[0][h << 6];
    const _Float16* pb1 = &p_buf[1][h << 6];
    const h2 one2 = h2{(_Float16)1.0f, (_Float16)1.0f};

    #pragma unroll 2
    for (int t = 1; t < T; ++t) {
        // raw barrier: drain LDS only; global loads stay in flight
        asm volatile("s_waitcnt lgkmcnt(0)\n\ts_barrier" ::: "memory");

        const int cur = t & 1, prv = cur ^ 1;
        const _Float16* pbase = prv ? pb1 : pb0;

        float acc0 = 0.f, acc1 = 0.f, acc2 = 0.f, acc3 = 0.f;   // matvec
        float ps0 = 0.f, ps1 = 0.f, ps2 = 0.f, ps3 = 0.f;       // p half-sum
        #pragma unroll
        for (int k = 0; k < 8; ++k) {
            const int cch = ((lane & 7) + k) & 7;
            const h8 pv = *reinterpret_cast<const h8*>(pbase + (cch << 3));
            const h2 v0 = __builtin_shufflevector(pv, pv, 0, 1);
            const h2 v1 = __builtin_shufflevector(pv, pv, 2, 3);
            const h2 v2 = __builtin_shufflevector(pv, pv, 4, 5);
            const h2 v3 = __builtin_shufflevector(pv, pv, 6, 7);
            acc0 = __builtin_amdgcn_fdot2(v0, e2[(k << 2) + 0], acc0, false);
            acc1 = __builtin_amdgcn_fdot2(v1, e2[(k << 2) + 1], acc1, false);
            acc2 = __builtin_amdgcn_fdot2(v2, e2[(k << 2) + 2], acc2, false);
            acc3 = __builtin_amdgcn_fdot2(v3, e2[(k << 2) + 3], acc3, false);
            ps0 = __builtin_amdgcn_fdot2(v0, one2, ps0, false);
            ps1 = __builtin_amdgcn_fdot2(v1, one2, ps1, false);
            ps2 = __builtin_amdgcn_fdot2(v2, one2, ps2, false);
            ps3 = __builtin_amdgcn_fdot2(v3, one2, ps3, false);
        }
        const float s = (acc0 + acc1) + (acc2 + acc3);
        const float ph = (ps0 + ps1) + (ps2 + ps3);

        // cross-half sums via permlane32_swap (VALU)
        float x = s, y = s;
        asm volatile("v_permlane32_swap_b32 %0, %1" : "+v"(x), "+v"(y));
        const float stot = x + y;
        float u = ph, v = ph;
        asm volatile("v_permlane32_swap_b32 %0, %1" : "+v"(u), "+v"(v));
        const float psum = fmaxf(u + v, 1e-30f);

        // self-referential rescale: sc = 1/psum (off dependent path)
        const float sc = __builtin_amdgcn_rcpf(psum);
        Mtot += __log2f(psum);

        const float na = stot * (fx * sc);
        if (t == tlast) { svE = na; svM = Mtot; }

        if (h == 0) p_buf[cur][j] = (_Float16)na;

        // prefetch raw(t+3); produce fx for t+1 from (rB,gB)
        float rN = 0.0f; int gN = 1;
        if (t + 3 < T) {
            rN = emP[(size_t)(t + 3) * N];
            if (sup) gN = tgP[(size_t)(t + 3) * N];
        }
        fx = gB ? __expf(rB) : 0.0f;
        rB = rC; gB = gC;
        rC = rN; gC = gN;
    }

    // ---- z = LN2*svM + log( sum_j svE_j * exp(en_j) ); j duplicated x2 ----
    const float en = end_forb[j] ? IMPOSSIBLE : end_tr[j];
    float term = svE * __expf(en);

    #pragma unroll
    for (int d = 1; d < 64; d <<= 1) term += __shfl_xor(term, d);
    __syncthreads();
    if (lane == 0) wred[wave] = term;
    __syncthreads();
    const float tot = (wred[0] + wred[1]) + (wred[2] + wred[3]);  // = 2 * sum
    const float z = LN2 * svM + __logf(tot * 0.5f);

    if (tid == 0) z_ws[chain] = z;
}

__global__ void crf_combine_kernel(const float* __restrict__ z_ws,
                                   float* __restrict__ out) {
    const int b = (int)threadIdx.x;
    if (b < B) out[b] = z_ws[B + b] - z_ws[b];
}

extern "C" void kernel_launch(void* const* d_in, const int* in_sizes, int n_in,
                              void* d_out, int out_size, void* d_ws, size_t ws_size,
                              hipStream_t stream) {
    const float* emissions = (const float*)d_in[0];
    const int* mask = (const int*)d_in[1];
    const int* target = (const int*)d_in[2];
    const float* transitions = (const float*)d_in[3];
    const float* start_tr = (const float*)d_in[4];
    const float* end_tr = (const float*)d_in[5];
    const int* forb = (const int*)d_in[6];
    const int* start_forb = (const int*)d_in[7];
    const int* end_forb = (const int*)d_in[8];
    float* out = (float*)d_out;
    float* z_ws = (float*)d_ws;

    crf_chain_kernel<<<dim3(2 * B), dim3(256), 0, stream>>>(
        emissions, mask, target, transitions, start_tr, end_tr,
        forb, start_forb, end_forb, z_ws);
    crf_combine_kernel<<<dim3(1), dim3(64), 0, stream>>>(z_ws, out);
}